// Round 17
// baseline (964.556 us; speedup 1.0000x reference)
//
#include <hip/hip_runtime.h>
#include <stdint.h>

#define N_NODES 20000
#define N_EDGES 320000
#define E_TOT   (N_EDGES + N_NODES)
#define NGRAPH  64
#define DIN     64
#define DHID    128
#define NHEAD   8
#define HDIM    1024

typedef unsigned int u32;
typedef unsigned short u16;
typedef __bf16 bfx8 __attribute__((ext_vector_type(8)));
typedef float f32x4 __attribute__((ext_vector_type(4)));
typedef float f32x2 __attribute__((ext_vector_type(2)));

// fp32 -> bf16 round-to-nearest-even
__device__ __forceinline__ u16 f2bf(float f){
  u32 u = __float_as_uint(f);
  u32 r = (u + 0x7FFFu + ((u >> 16) & 1u)) >> 16;
  return (u16)r;
}
__device__ __forceinline__ float bf2f(u16 v){
  return __uint_as_float(((u32)v) << 16);
}

// async 16B global->LDS
typedef __attribute__((address_space(3))) u32 lds_u32_t;
typedef const __attribute__((address_space(1))) u32 glb_u32_t;
__device__ __forceinline__ void g2l16(const void* g, void* l){
  __builtin_amdgcn_global_load_lds((glb_u32_t*)(uintptr_t)g,
                                   (lds_u32_t*)(uintptr_t)l, 16, 0, 0);
}

// ---------------- Threefry-2x32 (JAX), 20 rounds ----------------
__device__ __forceinline__ u32 rotl32(u32 x, int r){ return (x<<r) | (x>>(32-r)); }

__device__ __forceinline__ void threefry2x32(u32 k0, u32 k1, u32 x0, u32 x1,
                                             u32& y0, u32& y1){
  u32 k2 = k0 ^ k1 ^ 0x1BD11BDAu;
  x0 += k0; x1 += k1;
#define TFR(r) { x0 += x1; x1 = rotl32(x1, (r)); x1 ^= x0; }
  TFR(13) TFR(15) TFR(26) TFR(6)
  x0 += k1; x1 += k2 + 1u;
  TFR(17) TFR(29) TFR(16) TFR(24)
  x0 += k2; x1 += k0 + 2u;
  TFR(13) TFR(15) TFR(26) TFR(6)
  x0 += k0; x1 += k1 + 3u;
  TFR(17) TFR(29) TFR(16) TFR(24)
  x0 += k1; x1 += k2 + 4u;
  TFR(13) TFR(15) TFR(26) TFR(6)
  x0 += k2; x1 += k0 + 5u;
#undef TFR
  y0 = x0; y1 = x1;
}

// XLA ErfInv32 (Giles polynomial); fast log via v_log_f32
__device__ __forceinline__ float erfinv_fast(float x){
  float t = fmaf(-x, x, 1.0f);     // 1 - x^2
  float w = -__logf(t);
  float p;
  if (w < 5.0f){
    w -= 2.5f;
    p = 2.81022636e-08f;
    p = fmaf(p, w, 3.43273939e-07f);
    p = fmaf(p, w, -3.5233877e-06f);
    p = fmaf(p, w, -4.39150654e-06f);
    p = fmaf(p, w, 0.00021858087f);
    p = fmaf(p, w, -0.00125372503f);
    p = fmaf(p, w, -0.00417768164f);
    p = fmaf(p, w, 0.246640727f);
    p = fmaf(p, w, 1.50140941f);
  } else {
    w = sqrtf(w) - 3.0f;
    p = -0.000200214257f;
    p = fmaf(p, w, 0.000100950558f);
    p = fmaf(p, w, 0.00134934322f);
    p = fmaf(p, w, -0.00367342844f);
    p = fmaf(p, w, 0.00573950773f);
    p = fmaf(p, w, -0.0076224613f);
    p = fmaf(p, w, 0.00943887047f);
    p = fmaf(p, w, 1.00167406f);
    p = fmaf(p, w, 2.83297682f);
  }
  return p * x;
}

__device__ __forceinline__ float jax_normal(u32 seed, u32 i){
  u32 y0, y1;
  threefry2x32(0u, seed, 0u, i, y0, y1);
  u32 bits = y0 ^ y1;
  float f = __uint_as_float((bits >> 9) | 0x3f800000u) - 1.0f;   // [0,1)
  float xx = fmaxf(-0.99999994f, fmaf(f, 2.0f, -0.99999994f));   // [lo,1)
  return 1.41421356f * erfinv_fast(xx);
}

// ---------------- prep: converts + CSR counts in ONE launch ----------------
// z=0: bootW0->bf16, z=1: bootW1->bf16, z=2: x->bf16, z=3: count atomics
__global__ __launch_bounds__(256) void prep_misc_kernel(const float* __restrict__ x,
    const float* __restrict__ W0, const float* __restrict__ W1,
    u16* __restrict__ xbf, u16* __restrict__ O0, u16* __restrict__ O1,
    const int* __restrict__ ei, const int* __restrict__ batch,
    int* __restrict__ cnt, int* __restrict__ gcnt){
  const int z = blockIdx.y;
  if (z < 3){
    const float* S = (z==0) ? W0 : (z==1) ? W1 : x;
    u16* D = (z==0) ? O0 : (z==1) ? O1 : xbf;
    const int total = (z==2) ? N_NODES*DIN : HDIM*HDIM;
    int i = (blockIdx.x*256 + threadIdx.x)*4;
    if (i < total){
      float4 v = *(const float4*)(S + i);
      D[i+0] = f2bf(v.x); D[i+1] = f2bf(v.y);
      D[i+2] = f2bf(v.z); D[i+3] = f2bf(v.w);
    }
  } else {
    int i = blockIdx.x*256 + threadIdx.x;
    if (i < N_EDGES) atomicAdd(&cnt[ei[N_EDGES + i]], 1);          // dst row
    else if (i < E_TOT) atomicAdd(&gcnt[batch[i - N_EDGES]], 1);
  }
}

// gatW0/1/2 transpose+convert; z selects.
__global__ __launch_bounds__(256) void transpose_all_kernel(
    const float* __restrict__ W0, const float* __restrict__ W1,
    const float* __restrict__ W2,
    u16* __restrict__ T0, u16* __restrict__ T1, u16* __restrict__ T2){
  const int z = blockIdx.z;
  const float* W = (z==0)?W0:(z==1)?W1:W2;
  u16* T = (z==0)?T0:(z==1)?T1:T2;
  const int K = (z==0)?DIN:HDIM;
  const int bk = blockIdx.y*32;
  if (bk >= K) return;
  __shared__ float t[32][33];
  int bn = blockIdx.x*32;
  int lx = threadIdx.x & 31, ly = threadIdx.x >> 5;   // 32 x 8
#pragma unroll
  for (int r = 0; r < 32; r += 8)
    t[ly+r][lx] = W[(size_t)(bk+ly+r)*HDIM + bn + lx];
  __syncthreads();
#pragma unroll
  for (int r = 0; r < 32; r += 8)
    T[(size_t)(bn+ly+r)*K + bk + lx] = f2bf(t[lx][ly+r]);
}

// ---------------- CSR scan (block 0, writes self-loops) + gcnt scan -------
__global__ __launch_bounds__(1024) void scan_pair_kernel(const int* __restrict__ cnt,
    int* __restrict__ rowptr, int* __restrict__ cursor, int* __restrict__ colidx,
    const int* __restrict__ gcnt, int* __restrict__ goff){
  if (blockIdx.x == 1){
    if (threadIdx.x == 0){
      int s = 0;
      for (int g = 0; g < NGRAPH; ++g){ goff[g] = s; s += gcnt[g]; }
      goff[NGRAPH] = s;
    }
    return;
  }
  __shared__ int wsum[16];
  __shared__ int carry_s;
  const int tid = threadIdx.x, lane = tid & 63, wv = tid >> 6;
  if (tid == 0){ carry_s = 0; rowptr[0] = 0; }
  __syncthreads();
  for (int base = 0; base < N_NODES; base += 1024){
    int i = base + tid;
    int v = (i < N_NODES) ? cnt[i] + 1 : 0;      // +1 self-loop
    int s = v;
#pragma unroll
    for (int off = 1; off < 64; off <<= 1){
      int t = __shfl_up(s, off);
      if (lane >= off) s += t;
    }
    if (lane == 63) wsum[wv] = s;
    __syncthreads();
    if (wv == 0 && lane < 16){
      int ws = wsum[lane];
#pragma unroll
      for (int off = 1; off < 16; off <<= 1){
        int t = __shfl_up(ws, off);
        if (lane >= off) ws += t;
      }
      wsum[lane] = ws;
    }
    __syncthreads();
    int incl = s + ((wv > 0) ? wsum[wv-1] : 0) + carry_s;
    if (i < N_NODES){
      rowptr[i+1] = incl;
      const int slot = incl - v;       // row base
      colidx[slot] = i;                // self-loop FIRST (R5 ordering anchor)
      cursor[i] = slot + 1;            // edges fill after
    }
    __syncthreads();
    if (tid == 1023) carry_s = incl;
    __syncthreads();
  }
}

__global__ __launch_bounds__(256) void fill_edges_kernel(const int* __restrict__ ei,
    int* __restrict__ cursor, int* __restrict__ colidx){
  int e = blockIdx.x*256 + threadIdx.x;
  if (e < N_EDGES){
    int s = ei[e], d = ei[N_EDGES + e];
    int p = atomicAdd(&cursor[d], 1);
    colidx[p] = s;
  }
}

// ---------------- bf16 MFMA GEMM (shared body, BK=64) ----------------
// C tile of A[M,K] @ BT[1024,K]^T (+bias fp32), bf16 out; optional fused
// attention logits. BK=64 halves the barrier/vmcnt-drain count vs BK=32
// (K-loop was latency-bound at 25% occupancy). MFMA order per (i,j) stays
// ascending-k (half 0 then half 1) -> bit-identical accumulators.
__device__ __forceinline__ void gemm_tile(const u16* __restrict__ A,
    const u16* __restrict__ BT, const float* __restrict__ bias,
    u16* __restrict__ Cb, int M, int K, int bm, int bn,
    u16* As, u16* Bs,
    const float* __restrict__ asrc, const float* __restrict__ adst,
    float* __restrict__ sbuf, float* __restrict__ tbuf){
  const int tid = threadIdx.x;
  const int lane = tid & 63, w = tid >> 6;
  const int wm = (w & 1)*64, wn = (w >> 1)*64;

  // staging: 1024 16B-chunks per matrix (128 rows x 8 kc); 4 per thread
  const u16* agp[4]; const u16* bgp[4];
  u16 *alp[4], *blp[4];
#pragma unroll
  for (int q = 0; q < 4; ++q){
    const int cid = q*256 + tid;
    const int rr = cid & 127, kc = cid >> 7;
    int ar = bm + rr; if (ar >= M) ar = M - 1;
    agp[q] = A + (size_t)ar*K + kc*8;
    bgp[q] = BT + (size_t)(bn + rr)*K + kc*8;
    alp[q] = As + cid*8;
    blp[q] = Bs + cid*8;
  }

  const int rowl = lane & 15, kg = lane >> 4;

  f32x4 acc[4][4] = {};                       // [j][i] (operand-swapped)
  for (int k0 = 0; k0 < K; k0 += 64){
#pragma unroll
    for (int q = 0; q < 4; ++q){
      g2l16(agp[q] + k0, alp[q]);
      g2l16(bgp[q] + k0, blp[q]);
    }
    __syncthreads();
#pragma unroll
    for (int h = 0; h < 2; ++h){
      const bfx8* aph = (const bfx8*)(As + (((size_t)h*4 + kg)*128 + wm + rowl)*8);
      const bfx8* bph = (const bfx8*)(Bs + (((size_t)h*4 + kg)*128 + wn + rowl)*8);
      bfx8 af[4], bfr[4];
#pragma unroll
      for (int i = 0; i < 4; ++i){ af[i] = aph[i*16]; bfr[i] = bph[i*16]; }
#pragma unroll
      for (int i = 0; i < 4; ++i)
#pragma unroll
        for (int j = 0; j < 4; ++j)
          acc[j][i] = __builtin_amdgcn_mfma_f32_16x16x32_bf16(bfr[j], af[i], acc[j][i], 0, 0, 0);
    }
    __syncthreads();
  }

  const int quad = lane >> 4;
  const bool dost = (sbuf != nullptr);
  const int head = bn >> 7;
  float sl[4] = {0.f,0.f,0.f,0.f}, tl[4] = {0.f,0.f,0.f,0.f};
#pragma unroll
  for (int j = 0; j < 4; ++j){
    const int col0 = bn + wn + j*16 + quad*4;
    float4 bv = make_float4(0.f,0.f,0.f,0.f);
    if (bias) bv = *(const float4*)(bias + col0);
    float4 av = make_float4(0.f,0.f,0.f,0.f), dv = av;
    if (dost){
      const int d0 = col0 - bn;                  // head-local dim
      av = *(const float4*)(asrc + head*DHID + d0);
      dv = *(const float4*)(adst + head*DHID + d0);
    }
#pragma unroll
    for (int i = 0; i < 4; ++i){
      const int row = bm + wm + i*16 + rowl;
      const u16 p0 = f2bf(acc[j][i][0] + bv.x);
      const u16 p1 = f2bf(acc[j][i][1] + bv.y);
      const u16 p2 = f2bf(acc[j][i][2] + bv.z);
      const u16 p3 = f2bf(acc[j][i][3] + bv.w);
      if (row < M){
        uint2 pk;
        pk.x = (u32)p0 | ((u32)p1 << 16);
        pk.y = (u32)p2 | ((u32)p3 << 16);
        *(uint2*)(Cb + (size_t)row*HDIM + col0) = pk;
      }
      if (dost){
        const float c0 = bf2f(p0), c1 = bf2f(p1), c2 = bf2f(p2), c3 = bf2f(p3);
        sl[i] = fmaf(c0, av.x, fmaf(c1, av.y, fmaf(c2, av.z, fmaf(c3, av.w, sl[i]))));
        tl[i] = fmaf(c0, dv.x, fmaf(c1, dv.y, fmaf(c2, dv.z, fmaf(c3, dv.w, tl[i]))));
      }
    }
  }
  if (dost){
#pragma unroll
    for (int i = 0; i < 4; ++i){
      sl[i] += __shfl_xor(sl[i], 16); sl[i] += __shfl_xor(sl[i], 32);
      tl[i] += __shfl_xor(tl[i], 16); tl[i] += __shfl_xor(tl[i], 32);
    }
    // cross-wave (wn) combine via dead As buffer
    float* sred = (float*)As;        // [128]
    float* tred = sred + 128;        // [128]
    if ((w >> 1) == 0 && quad == 0){
#pragma unroll
      for (int i = 0; i < 4; ++i){
        const int rl = wm + i*16 + rowl;
        sred[rl] = sl[i]; tred[rl] = tl[i];
      }
    }
    __syncthreads();
    if ((w >> 1) == 1 && quad == 0){
#pragma unroll
      for (int i = 0; i < 4; ++i){
        const int rl = wm + i*16 + rowl;
        const int row = bm + rl;
        if (row < M){
          sbuf[row*NHEAD + head] = sred[rl] + sl[i];
          tbuf[row*NHEAD + head] = tred[rl] + tl[i];
        }
      }
    }
  }
}

// main GEMM: XCD-aware swizzle (R10), fused st epilogue
__global__ __launch_bounds__(256) void gemm_bf16(
    const u16* __restrict__ A, const u16* __restrict__ BT,
    const float* __restrict__ bias, u16* __restrict__ Cb, int M, int K,
    const float* __restrict__ asrc, const float* __restrict__ adst,
    float* __restrict__ sbuf, float* __restrict__ tbuf){
  __shared__ __align__(16) u16 As[8*128*8];   // 16 KB
  __shared__ __align__(16) u16 Bs[8*128*8];   // 16 KB
  const int kblk = blockIdx.y*8 + blockIdx.x;
  const int xc = kblk & 7, bq = (kblk >> 3) & 7, gq = kblk >> 6;
  const int bmi = gq*8 + xc;                  // row-tile index
  const int mt = (M + 127) >> 7;
  if (bmi >= mt) return;
  gemm_tile(A, BT, bias, Cb, M, K, bmi*128, bq*128, As, Bs,
            asrc, adst, sbuf, tbuf);
}

// weight-fusion GEMMs (z=0,1) + fused-bias reductions (z=2) in one launch
__global__ __launch_bounds__(256) void wf_bias_kernel(
    const u16* __restrict__ A0, const u16* __restrict__ B0, u16* __restrict__ C0,
    const u16* __restrict__ A1, const u16* __restrict__ B1, u16* __restrict__ C1,
    const float* __restrict__ bb0, const u16* __restrict__ gwt0,
    const float* __restrict__ bb1, const u16* __restrict__ gwt1,
    float* __restrict__ fb0, float* __restrict__ fb1){
  __shared__ __align__(16) u16 As[8*128*8];
  __shared__ __align__(16) u16 Bs[8*128*8];
  if (blockIdx.z < 2){
    const u16* A = blockIdx.z ? A1 : A0;
    const u16* B = blockIdx.z ? B1 : B0;
    u16* C = blockIdx.z ? C1 : C0;
    gemm_tile(A, B, nullptr, C, HDIM, HDIM, blockIdx.y*128, blockIdx.x*128,
              As, Bs, nullptr, nullptr, nullptr, nullptr);
  } else {
    const int kb = blockIdx.y*8 + blockIdx.x;          // 0..63
    const int wv = threadIdx.x >> 6, lane = threadIdx.x & 63;
    for (int idx = kb*4 + wv; idx < 2*HDIM; idx += 256){
      const int set = idx >> 10, n = idx & (HDIM-1);
      const float* bb = set ? bb1 : bb0;
      const u16* row = (set ? gwt1 : gwt0) + (size_t)n*HDIM + lane*16;
      const float* bp = bb + lane*16;
      float acc = 0.f;
#pragma unroll
      for (int k = 0; k < 16; ++k) acc = fmaf(bp[k], bf2f(row[k]), acc);
      for (int off = 32; off > 0; off >>= 1) acc += __shfl_down(acc, off);
      if (lane == 0) (set ? fb1 : fb0)[n] = acc;
    }
  }
}

// ---------------- GAT aggregation (R5 structure; scalar-addressed gather) -
__global__ __launch_bounds__(256) void gat_agg_kernel(const u16* __restrict__ hlin,
    const float* __restrict__ sbuf, const float* __restrict__ tbuf,
    const int* __restrict__ rowptr, const int* __restrict__ colidx,
    const float* __restrict__ bias, float* __restrict__ outf,
    u16* __restrict__ outbf, u32 seed){
  __shared__ float esh[64*NHEAD];
  __shared__ int   srcs[64];              // byte offsets (node*2048)
  __shared__ float tn[NHEAD], mh[NHEAD], dsum[NHEAD], resc[NHEAD];
  const int n = blockIdx.x;
  const int tid = threadIdx.x;
  const int ht = tid >> 5;                 // head of this thread's 4 dims
  if (tid < NHEAD){
    tn[tid] = tbuf[n*NHEAD + tid];
    mh[tid] = -INFINITY;
    dsum[tid] = 0.0f;
  }
  const int row0 = rowptr[n];
  const int deg = rowptr[n+1] - row0;      // >=1 (self-loop)
  const char* hl = (const char*)hlin;
  const u32 tid8 = (u32)tid*8u;            // per-thread byte offset
  const char* sbase = (const char*)sbuf;
  f32x2 a01 = {0.f,0.f}, a23 = {0.f,0.f};
  f32x2 b01 = {0.f,0.f}, b23 = {0.f,0.f};
  for (int c = 0; c < deg; c += 64){
    const int nc = min(64, deg - c);
    __syncthreads();
    if (tid < nc) srcs[tid] = colidx[row0 + c + tid] << 11;   // *HDIM*2 bytes
    __syncthreads();
    for (int it = tid; it < nc*NHEAD; it += 256){
      int j = it >> 3, hh = it & 7;
      const float* sp = (const float*)(sbase + (srcs[j] >> 6));  // *NHEAD*4 bytes
      float e = sp[hh] + tn[hh];
      esh[it] = (e > 0.f) ? e : 0.2f*e;     // leaky_relu 0.2
    }
    __syncthreads();
    if (tid < 64){                          // wave0: parallel softmax (8 lanes/head)
      const int hh = tid & 7, slot = tid >> 3;
      float mc = -INFINITY;
      for (int j = slot; j < nc; j += 8) mc = fmaxf(mc, esh[j*NHEAD+hh]);
      mc = fmaxf(mc, __shfl_xor(mc, 8));
      mc = fmaxf(mc, __shfl_xor(mc, 16));
      mc = fmaxf(mc, __shfl_xor(mc, 32));
      const float mold = mh[hh];
      const float mnew = fmaxf(mold, mc);
      float wsum = 0.f;
      for (int j = slot; j < nc; j += 8){
        float w = __expf(esh[j*NHEAD+hh] - mnew);
        esh[j*NHEAD+hh] = w;
        wsum += w;
      }
      wsum += __shfl_xor(wsum, 8);
      wsum += __shfl_xor(wsum, 16);
      wsum += __shfl_xor(wsum, 32);
      if (slot == 0){
        float r = (mold == -INFINITY) ? 0.0f : __expf(mold - mnew);
        dsum[hh] = fmaf(dsum[hh], r, wsum);
        mh[hh] = mnew;
        resc[hh] = r;
      }
    }
    __syncthreads();
    const float r = resc[ht];
    const f32x2 r2 = {r, r};
    a01 *= r2; a23 *= r2; b01 *= r2; b23 *= r2;
    int j = 0;
    for (; j + 2 <= nc; j += 2){
      const float w0 = esh[j*NHEAD + ht];
      const float w1 = esh[(j+1)*NHEAD + ht];
      const char* rp0 = hl + (u32)__builtin_amdgcn_readfirstlane(srcs[j]);
      const char* rp1 = hl + (u32)__builtin_amdgcn_readfirstlane(srcs[j+1]);
      const uint2 h0 = *(const uint2*)(rp0 + tid8);
      const uint2 h1 = *(const uint2*)(rp1 + tid8);
      const f32x2 w02 = {w0, w0}, w12 = {w1, w1};
      f32x2 v;
      v.x = __uint_as_float(h0.x << 16); v.y = __uint_as_float(h0.x & 0xffff0000u);
      a01 = __builtin_elementwise_fma(w02, v, a01);
      v.x = __uint_as_float(h0.y << 16); v.y = __uint_as_float(h0.y & 0xffff0000u);
      a23 = __builtin_elementwise_fma(w02, v, a23);
      v.x = __uint_as_float(h1.x << 16); v.y = __uint_as_float(h1.x & 0xffff0000u);
      b01 = __builtin_elementwise_fma(w12, v, b01);
      v.x = __uint_as_float(h1.y << 16); v.y = __uint_as_float(h1.y & 0xffff0000u);
      b23 = __builtin_elementwise_fma(w12, v, b23);
    }
    if (j < nc){
      const float w0 = esh[j*NHEAD + ht];
      const char* rp0 = hl + (u32)__builtin_amdgcn_readfirstlane(srcs[j]);
      const uint2 h0 = *(const uint2*)(rp0 + tid8);
      const f32x2 w02 = {w0, w0};
      f32x2 v;
      v.x = __uint_as_float(h0.x << 16); v.y = __uint_as_float(h0.x & 0xffff0000u);
      a01 = __builtin_elementwise_fma(w02, v, a01);
      v.x = __uint_as_float(h0.y << 16); v.y = __uint_as_float(h0.y & 0xffff0000u);
      a23 = __builtin_elementwise_fma(w02, v, a23);
    }
  }
  float4 acc = make_float4(a01.x + b01.x, a01.y + b01.y,
                           a23.x + b23.x, a23.y + b23.y);
  const float inv = 1.0f / fmaxf(dsum[ht], 1e-16f);
  const float4 bv = *(const float4*)(bias + tid*4);
  float4 o;
  o.x = fmaf(acc.x, inv, bv.x);
  o.y = fmaf(acc.y, inv, bv.y);
  o.z = fmaf(acc.z, inv, bv.z);
  o.w = fmaf(acc.w, inv, bv.w);
  o.x = (o.x > 0.f) ? o.x : __expf(o.x) - 1.0f;   // elu (fast)
  o.y = (o.y > 0.f) ? o.y : __expf(o.y) - 1.0f;
  o.z = (o.z > 0.f) ? o.z : __expf(o.z) - 1.0f;
  o.w = (o.w > 0.f) ? o.w : __expf(o.w) - 1.0f;
  if (outbf){
    const u32 ib = (u32)(n*HDIM + tid*4);
    ushort4 ov;
    ov.x = f2bf(fmaf(0.1f, jax_normal(seed, ib+0u), o.x));
    ov.y = f2bf(fmaf(0.1f, jax_normal(seed, ib+1u), o.y));
    ov.z = f2bf(fmaf(0.1f, jax_normal(seed, ib+2u), o.z));
    ov.w = f2bf(fmaf(0.1f, jax_normal(seed, ib+3u), o.w));
    *(ushort4*)(outbf + (size_t)n*HDIM + tid*4) = ov;
  } else {
    *(float4*)(outf + (size_t)n*HDIM + tid*4) = o;
  }
}

// ---------------- mean pool + classifier (one kernel, LDS gpool) ----------
__global__ __launch_bounds__(256) void pool_clf_kernel(const float* __restrict__ h,
    const int* __restrict__ goff, const int* __restrict__ gcnt,
    const float* __restrict__ W1, const float* __restrict__ b1,
    const float* __restrict__ W2, const float* __restrict__ b2,
    float* __restrict__ out){
  __shared__ float gs[HDIM];
  __shared__ float z[DHID];
  const int g = blockIdx.x, tid = threadIdx.x;
  const int cb = tid*4;
  float4 acc = make_float4(0.f,0.f,0.f,0.f);
  const int n0 = goff[g], n1 = goff[g+1];
  for (int n = n0; n < n1; ++n){
    const float4 v = *(const float4*)(h + (size_t)n*HDIM + cb);
    acc.x += v.x; acc.y += v.y; acc.z += v.z; acc.w += v.w;
  }
  const float invc = 1.0f / fmaxf((float)gcnt[g], 1.0f);
  gs[cb+0] = acc.x*invc; gs[cb+1] = acc.y*invc;
  gs[cb+2] = acc.z*invc; gs[cb+3] = acc.w*invc;
  __syncthreads();
  if (tid < DHID){
    float a = b1[tid];
    for (int k = 0; k < HDIM; ++k) a = fmaf(gs[k], W1[k*DHID + tid], a);
    z[tid] = fmaxf(a, 0.0f);
  }
  __syncthreads();
  if (tid < 2){
    float o = b2[tid];
    for (int k = 0; k < DHID; ++k) o = fmaf(z[k], W2[k*2 + tid], o);
    out[g*2 + tid] = o;
  }
}

// ---------------- launch ----------------
extern "C" void kernel_launch(void* const* d_in, const int* in_sizes, int n_in,
                              void* d_out, int out_size, void* d_ws, size_t ws_size,
                              hipStream_t stream){
  const float* x      = (const float*)d_in[0];
  const int*   ei     = (const int*)d_in[1];
  const int*   batch  = (const int*)d_in[2];
  const float* gatW[3]  = {(const float*)d_in[3],  (const float*)d_in[7],  (const float*)d_in[11]};
  const float* gatB[3]  = {(const float*)d_in[4],  (const float*)d_in[8],  (const float*)d_in[12]};
  const float* asrc[3]  = {(const float*)d_in[5],  (const float*)d_in[9],  (const float*)d_in[13]};
  const float* adst[3]  = {(const float*)d_in[6],  (const float*)d_in[10], (const float*)d_in[14]};
  const float* bootW[2] = {(const float*)d_in[15], (const float*)d_in[17]};
  const float* bootB[2] = {(const float*)d_in[16], (const float*)d_in[18]};
  const float* clfW1 = (const float*)d_in[19];
  const float* clfb1 = (const float*)d_in[20];
  const float* clfW2 = (const float*)d_in[21];
  const float* clfb2 = (const float*)d_in[22];
  float* outp = (float*)d_out;

  // ---- workspace layout ----
  float* fws  = (float*)d_ws;
  float* hB   = fws;                               // N*HD fp32 (GAT L2 out)
  float* sbuf = hB + (size_t)N_NODES*HDIM;         // N*H
  float* tbuf = sbuf + (size_t)N_NODES*NHEAD;      // N*H
  float* fbias0 = tbuf + (size_t)N_NODES*NHEAD;    // HD fp32 (bootB0 @ gatW1)
  float* fbias1 = fbias0 + HDIM;                   // HD fp32 (bootB1 @ gatW2)
  u16* xbf    = (u16*)(fbias1 + HDIM);             // N*DIN bf16
  u16* hAbf   = xbf + (size_t)N_NODES*DIN;         // N*HD bf16 (GAT linear out)
  u16* hBbf   = hAbf + (size_t)N_NODES*HDIM;       // N*HD bf16 (GAT+noise out)
  u16* wt[3];
  wt[0] = hBbf + (size_t)N_NODES*HDIM;             // gatW0^T [1024,64]
  wt[1] = wt[0] + (size_t)HDIM*DIN;                // gatW1^T [1024,1024]
  wt[2] = wt[1] + (size_t)HDIM*HDIM;               // gatW2^T
  u16* wnt0   = wt[2] + (size_t)HDIM*HDIM;         // bootW0 bf16 (row-major)
  u16* wnt1   = wnt0 + (size_t)HDIM*HDIM;          // bootW1 bf16 (row-major)
  u16* wf0    = wnt1 + (size_t)HDIM*HDIM;          // (bootW0@gatW1)^T bf16
  u16* wf1    = wf0 + (size_t)HDIM*HDIM;           // (bootW1@gatW2)^T bf16
  int* rowptr = (int*)(wf1 + (size_t)HDIM*HDIM);   // N+1
  int* cursor = rowptr + (N_NODES+1);              // N
  int* colidx = cursor + N_NODES;                  // E_TOT
  int* gcnt   = colidx + E_TOT;                    // G   (adjacent to cnt: one memset)
  int* cnt    = gcnt + NGRAPH;                     // N
  int* goff   = cnt + N_NODES;                     // G+1

  hipMemsetAsync(gcnt, 0, (NGRAPH + N_NODES)*sizeof(int), stream);

  const int nb_e = (N_EDGES + 255)/256;

  // converts (x, bootW0, bootW1) + CSR/graph counts in one launch
  prep_misc_kernel<<<dim3((E_TOT + 255)/256, 4), 256, 0, stream>>>(
      x, bootW[0], bootW[1], xbf, wnt0, wnt1, ei, batch, cnt, gcnt);
  transpose_all_kernel<<<dim3(HDIM/32, HDIM/32, 3), 256, 0, stream>>>(
      gatW[0], gatW[1], gatW[2], wt[0], wt[1], wt[2]);
  scan_pair_kernel<<<2, 1024, 0, stream>>>(cnt, rowptr, cursor, colidx, gcnt, goff);
  fill_edges_kernel<<<nb_e, 256, 0, stream>>>(ei, cursor, colidx);

  // fused weights wf[n,k] = sum_m gatW^T[n,m]*bootW[k,m] + fused biases
  wf_bias_kernel<<<dim3(8, 8, 3), 256, 0, stream>>>(
      wt[1], wnt0, wf0, wt[2], wnt1, wf1,
      bootB[0], wt[1], bootB[1], wt[2], fbias0, fbias1);

  // swizzled grid: 8 col-tiles x (row-tiles padded to multiple of 8)
  const int mt = (N_NODES + 127)/128;              // 157
  dim3 gemmGrid(8, (mt + 7)/8*8);                  // (8, 160)

  // L0 (gemm with fused s/t epilogue)
  gemm_bf16<<<gemmGrid, 256, 0, stream>>>(xbf, wt[0], nullptr, hAbf, N_NODES, DIN,
                                          asrc[0], adst[0], sbuf, tbuf);
  gat_agg_kernel<<<N_NODES, 256, 0, stream>>>(hAbf, sbuf, tbuf, rowptr, colidx,
                                              gatB[0], nullptr, hBbf, 100u);
  // L1 (fused boot0+gat1 linear)
  gemm_bf16<<<gemmGrid, 256, 0, stream>>>(hBbf, wf0, fbias0, hAbf, N_NODES, HDIM,
                                          asrc[1], adst[1], sbuf, tbuf);
  gat_agg_kernel<<<N_NODES, 256, 0, stream>>>(hAbf, sbuf, tbuf, rowptr, colidx,
                                              gatB[1], nullptr, hBbf, 101u);
  // L2 (fused boot1+gat2 linear)
  gemm_bf16<<<gemmGrid, 256, 0, stream>>>(hBbf, wf1, fbias1, hAbf, N_NODES, HDIM,
                                          asrc[2], adst[2], sbuf, tbuf);
  gat_agg_kernel<<<N_NODES, 256, 0, stream>>>(hAbf, sbuf, tbuf, rowptr, colidx,
                                              gatB[2], hB, nullptr, 0u);

  pool_clf_kernel<<<NGRAPH, 256, 0, stream>>>(hB, goff, gcnt,
                                              clfW1, clfb1, clfW2, clfb2, outp);
}

// Round 18
// 926.873 us; speedup vs baseline: 1.0407x; 1.0407x over previous
//
#include <hip/hip_runtime.h>
#include <stdint.h>

#define N_NODES 20000
#define N_EDGES 320000
#define E_TOT   (N_EDGES + N_NODES)
#define NGRAPH  64
#define DIN     64
#define DHID    128
#define NHEAD   8
#define HDIM    1024

typedef unsigned int u32;
typedef unsigned short u16;
typedef __bf16 bfx8 __attribute__((ext_vector_type(8)));
typedef float f32x4 __attribute__((ext_vector_type(4)));
typedef float f32x2 __attribute__((ext_vector_type(2)));

// fp32 -> bf16 round-to-nearest-even
__device__ __forceinline__ u16 f2bf(float f){
  u32 u = __float_as_uint(f);
  u32 r = (u + 0x7FFFu + ((u >> 16) & 1u)) >> 16;
  return (u16)r;
}
__device__ __forceinline__ float bf2f(u16 v){
  return __uint_as_float(((u32)v) << 16);
}

// async 16B global->LDS
typedef __attribute__((address_space(3))) u32 lds_u32_t;
typedef const __attribute__((address_space(1))) u32 glb_u32_t;
__device__ __forceinline__ void g2l16(const void* g, void* l){
  __builtin_amdgcn_global_load_lds((glb_u32_t*)(uintptr_t)g,
                                   (lds_u32_t*)(uintptr_t)l, 16, 0, 0);
}

// ---------------- Threefry-2x32 (JAX), 20 rounds ----------------
__device__ __forceinline__ u32 rotl32(u32 x, int r){ return (x<<r) | (x>>(32-r)); }

__device__ __forceinline__ void threefry2x32(u32 k0, u32 k1, u32 x0, u32 x1,
                                             u32& y0, u32& y1){
  u32 k2 = k0 ^ k1 ^ 0x1BD11BDAu;
  x0 += k0; x1 += k1;
#define TFR(r) { x0 += x1; x1 = rotl32(x1, (r)); x1 ^= x0; }
  TFR(13) TFR(15) TFR(26) TFR(6)
  x0 += k1; x1 += k2 + 1u;
  TFR(17) TFR(29) TFR(16) TFR(24)
  x0 += k2; x1 += k0 + 2u;
  TFR(13) TFR(15) TFR(26) TFR(6)
  x0 += k0; x1 += k1 + 3u;
  TFR(17) TFR(29) TFR(16) TFR(24)
  x0 += k1; x1 += k2 + 4u;
  TFR(13) TFR(15) TFR(26) TFR(6)
  x0 += k2; x1 += k0 + 5u;
#undef TFR
  y0 = x0; y1 = x1;
}

// XLA ErfInv32 (Giles polynomial); fast log via v_log_f32
__device__ __forceinline__ float erfinv_fast(float x){
  float t = fmaf(-x, x, 1.0f);     // 1 - x^2
  float w = -__logf(t);
  float p;
  if (w < 5.0f){
    w -= 2.5f;
    p = 2.81022636e-08f;
    p = fmaf(p, w, 3.43273939e-07f);
    p = fmaf(p, w, -3.5233877e-06f);
    p = fmaf(p, w, -4.39150654e-06f);
    p = fmaf(p, w, 0.00021858087f);
    p = fmaf(p, w, -0.00125372503f);
    p = fmaf(p, w, -0.00417768164f);
    p = fmaf(p, w, 0.246640727f);
    p = fmaf(p, w, 1.50140941f);
  } else {
    w = sqrtf(w) - 3.0f;
    p = -0.000200214257f;
    p = fmaf(p, w, 0.000100950558f);
    p = fmaf(p, w, 0.00134934322f);
    p = fmaf(p, w, -0.00367342844f);
    p = fmaf(p, w, 0.00573950773f);
    p = fmaf(p, w, -0.0076224613f);
    p = fmaf(p, w, 0.00943887047f);
    p = fmaf(p, w, 1.00167406f);
    p = fmaf(p, w, 2.83297682f);
  }
  return p * x;
}

__device__ __forceinline__ float jax_normal(u32 seed, u32 i){
  u32 y0, y1;
  threefry2x32(0u, seed, 0u, i, y0, y1);
  u32 bits = y0 ^ y1;
  float f = __uint_as_float((bits >> 9) | 0x3f800000u) - 1.0f;   // [0,1)
  float xx = fmaxf(-0.99999994f, fmaf(f, 2.0f, -0.99999994f));   // [lo,1)
  return 1.41421356f * erfinv_fast(xx);
}

// ---------------- prep: converts + CSR counts in ONE launch ----------------
// z=0: bootW0->bf16, z=1: bootW1->bf16, z=2: x->bf16, z=3: count atomics
__global__ __launch_bounds__(256) void prep_misc_kernel(const float* __restrict__ x,
    const float* __restrict__ W0, const float* __restrict__ W1,
    u16* __restrict__ xbf, u16* __restrict__ O0, u16* __restrict__ O1,
    const int* __restrict__ ei, const int* __restrict__ batch,
    int* __restrict__ cnt, int* __restrict__ gcnt){
  const int z = blockIdx.y;
  if (z < 3){
    const float* S = (z==0) ? W0 : (z==1) ? W1 : x;
    u16* D = (z==0) ? O0 : (z==1) ? O1 : xbf;
    const int total = (z==2) ? N_NODES*DIN : HDIM*HDIM;
    int i = (blockIdx.x*256 + threadIdx.x)*4;
    if (i < total){
      float4 v = *(const float4*)(S + i);
      D[i+0] = f2bf(v.x); D[i+1] = f2bf(v.y);
      D[i+2] = f2bf(v.z); D[i+3] = f2bf(v.w);
    }
  } else {
    int i = blockIdx.x*256 + threadIdx.x;
    if (i < N_EDGES) atomicAdd(&cnt[ei[N_EDGES + i]], 1);          // dst row
    else if (i < E_TOT) atomicAdd(&gcnt[batch[i - N_EDGES]], 1);
  }
}

// gatW0/1/2 transpose+convert; z selects.
__global__ __launch_bounds__(256) void transpose_all_kernel(
    const float* __restrict__ W0, const float* __restrict__ W1,
    const float* __restrict__ W2,
    u16* __restrict__ T0, u16* __restrict__ T1, u16* __restrict__ T2){
  const int z = blockIdx.z;
  const float* W = (z==0)?W0:(z==1)?W1:W2;
  u16* T = (z==0)?T0:(z==1)?T1:T2;
  const int K = (z==0)?DIN:HDIM;
  const int bk = blockIdx.y*32;
  if (bk >= K) return;
  __shared__ float t[32][33];
  int bn = blockIdx.x*32;
  int lx = threadIdx.x & 31, ly = threadIdx.x >> 5;   // 32 x 8
#pragma unroll
  for (int r = 0; r < 32; r += 8)
    t[ly+r][lx] = W[(size_t)(bk+ly+r)*HDIM + bn + lx];
  __syncthreads();
#pragma unroll
  for (int r = 0; r < 32; r += 8)
    T[(size_t)(bn+ly+r)*K + bk + lx] = f2bf(t[lx][ly+r]);
}

// ---------------- CSR scan (block 0, writes self-loops) + gcnt scan -------
__global__ __launch_bounds__(1024) void scan_pair_kernel(const int* __restrict__ cnt,
    int* __restrict__ rowptr, int* __restrict__ cursor, int* __restrict__ colidx,
    const int* __restrict__ gcnt, int* __restrict__ goff){
  if (blockIdx.x == 1){
    if (threadIdx.x == 0){
      int s = 0;
      for (int g = 0; g < NGRAPH; ++g){ goff[g] = s; s += gcnt[g]; }
      goff[NGRAPH] = s;
    }
    return;
  }
  __shared__ int wsum[16];
  __shared__ int carry_s;
  const int tid = threadIdx.x, lane = tid & 63, wv = tid >> 6;
  if (tid == 0){ carry_s = 0; rowptr[0] = 0; }
  __syncthreads();
  for (int base = 0; base < N_NODES; base += 1024){
    int i = base + tid;
    int v = (i < N_NODES) ? cnt[i] + 1 : 0;      // +1 self-loop
    int s = v;
#pragma unroll
    for (int off = 1; off < 64; off <<= 1){
      int t = __shfl_up(s, off);
      if (lane >= off) s += t;
    }
    if (lane == 63) wsum[wv] = s;
    __syncthreads();
    if (wv == 0 && lane < 16){
      int ws = wsum[lane];
#pragma unroll
      for (int off = 1; off < 16; off <<= 1){
        int t = __shfl_up(ws, off);
        if (lane >= off) ws += t;
      }
      wsum[lane] = ws;
    }
    __syncthreads();
    int incl = s + ((wv > 0) ? wsum[wv-1] : 0) + carry_s;
    if (i < N_NODES){
      rowptr[i+1] = incl;
      const int slot = incl - v;       // row base
      colidx[slot] = i;                // self-loop FIRST (R5 ordering anchor)
      cursor[i] = slot + 1;            // edges fill after
    }
    __syncthreads();
    if (tid == 1023) carry_s = incl;
    __syncthreads();
  }
}

__global__ __launch_bounds__(256) void fill_edges_kernel(const int* __restrict__ ei,
    int* __restrict__ cursor, int* __restrict__ colidx){
  int e = blockIdx.x*256 + threadIdx.x;
  if (e < N_EDGES){
    int s = ei[e], d = ei[N_EDGES + e];
    int p = atomicAdd(&cursor[d], 1);
    colidx[p] = s;
  }
}

// ---------------- bf16 MFMA GEMM (shared body, BK=32) ----------------
// C tile of A[M,K] @ BT[1024,K]^T (+bias fp32), bf16 out; optional fused
// attention logits (block's 128-col tile == one head; p values are the
// bf16-rounded C — identical bits to a post-hoc read of C).
__device__ __forceinline__ void gemm_tile(const u16* __restrict__ A,
    const u16* __restrict__ BT, const float* __restrict__ bias,
    u16* __restrict__ Cb, int M, int K, int bm, int bn,
    u16* As, u16* Bs,
    const float* __restrict__ asrc, const float* __restrict__ adst,
    float* __restrict__ sbuf, float* __restrict__ tbuf){
  const int tid = threadIdx.x;
  const int lane = tid & 63, w = tid >> 6;
  const int wm = (w & 1)*64, wn = (w >> 1)*64;

  const int cid0 = tid, cid1 = 256 + tid;
  const int r0 = cid0 & 127, kc0 = cid0 >> 7;
  const int r1 = cid1 & 127, kc1 = cid1 >> 7;
  int ar0 = bm + r0; if (ar0 >= M) ar0 = M - 1;
  int ar1 = bm + r1; if (ar1 >= M) ar1 = M - 1;
  const u16* ag0 = A + (size_t)ar0*K + kc0*8;
  const u16* ag1 = A + (size_t)ar1*K + kc1*8;
  const u16* bg0 = BT + (size_t)(bn + r0)*K + kc0*8;
  const u16* bg1 = BT + (size_t)(bn + r1)*K + kc1*8;
  u16* al0 = As + cid0*8;  u16* al1 = As + cid1*8;
  u16* bl0 = Bs + cid0*8;  u16* bl1 = Bs + cid1*8;

  const int rowl = lane & 15, kg = lane >> 4;
  const bfx8* ap = (const bfx8*)(As + ((size_t)kg*128 + wm + rowl)*8);
  const bfx8* bp = (const bfx8*)(Bs + ((size_t)kg*128 + wn + rowl)*8);

  f32x4 acc[4][4] = {};                       // [j][i] (operand-swapped)
  for (int k0 = 0; k0 < K; k0 += 32){
    g2l16(ag0 + k0, al0);
    g2l16(ag1 + k0, al1);
    g2l16(bg0 + k0, bl0);
    g2l16(bg1 + k0, bl1);
    __syncthreads();
    bfx8 af[4], bfr[4];
#pragma unroll
    for (int i = 0; i < 4; ++i){ af[i] = ap[i*16]; bfr[i] = bp[i*16]; }
#pragma unroll
    for (int i = 0; i < 4; ++i)
#pragma unroll
      for (int j = 0; j < 4; ++j)
        acc[j][i] = __builtin_amdgcn_mfma_f32_16x16x32_bf16(bfr[j], af[i], acc[j][i], 0, 0, 0);
    __syncthreads();
  }

  const int quad = lane >> 4;
  const bool dost = (sbuf != nullptr);
  const int head = bn >> 7;
  float sl[4] = {0.f,0.f,0.f,0.f}, tl[4] = {0.f,0.f,0.f,0.f};
#pragma unroll
  for (int j = 0; j < 4; ++j){
    const int col0 = bn + wn + j*16 + quad*4;
    float4 bv = make_float4(0.f,0.f,0.f,0.f);
    if (bias) bv = *(const float4*)(bias + col0);
    float4 av = make_float4(0.f,0.f,0.f,0.f), dv = av;
    if (dost){
      const int d0 = col0 - bn;                  // head-local dim
      av = *(const float4*)(asrc + head*DHID + d0);
      dv = *(const float4*)(adst + head*DHID + d0);
    }
#pragma unroll
    for (int i = 0; i < 4; ++i){
      const int row = bm + wm + i*16 + rowl;
      const u16 p0 = f2bf(acc[j][i][0] + bv.x);
      const u16 p1 = f2bf(acc[j][i][1] + bv.y);
      const u16 p2 = f2bf(acc[j][i][2] + bv.z);
      const u16 p3 = f2bf(acc[j][i][3] + bv.w);
      if (row < M){
        uint2 pk;
        pk.x = (u32)p0 | ((u32)p1 << 16);
        pk.y = (u32)p2 | ((u32)p3 << 16);
        *(uint2*)(Cb + (size_t)row*HDIM + col0) = pk;
      }
      if (dost){
        const float c0 = bf2f(p0), c1 = bf2f(p1), c2 = bf2f(p2), c3 = bf2f(p3);
        sl[i] = fmaf(c0, av.x, fmaf(c1, av.y, fmaf(c2, av.z, fmaf(c3, av.w, sl[i]))));
        tl[i] = fmaf(c0, dv.x, fmaf(c1, dv.y, fmaf(c2, dv.z, fmaf(c3, dv.w, tl[i]))));
      }
    }
  }
  if (dost){
#pragma unroll
    for (int i = 0; i < 4; ++i){
      sl[i] += __shfl_xor(sl[i], 16); sl[i] += __shfl_xor(sl[i], 32);
      tl[i] += __shfl_xor(tl[i], 16); tl[i] += __shfl_xor(tl[i], 32);
    }
    // cross-wave (wn) combine via dead As buffer
    float* sred = (float*)As;        // [128]
    float* tred = sred + 128;        // [128]
    if ((w >> 1) == 0 && quad == 0){
#pragma unroll
      for (int i = 0; i < 4; ++i){
        const int rl = wm + i*16 + rowl;
        sred[rl] = sl[i]; tred[rl] = tl[i];
      }
    }
    __syncthreads();
    if ((w >> 1) == 1 && quad == 0){
#pragma unroll
      for (int i = 0; i < 4; ++i){
        const int rl = wm + i*16 + rowl;
        const int row = bm + rl;
        if (row < M){
          sbuf[row*NHEAD + head] = sred[rl] + sl[i];
          tbuf[row*NHEAD + head] = tred[rl] + tl[i];
        }
      }
    }
  }
}

// main GEMM: XCD-aware swizzle (R10), fused st epilogue
__global__ __launch_bounds__(256) void gemm_bf16(
    const u16* __restrict__ A, const u16* __restrict__ BT,
    const float* __restrict__ bias, u16* __restrict__ Cb, int M, int K,
    const float* __restrict__ asrc, const float* __restrict__ adst,
    float* __restrict__ sbuf, float* __restrict__ tbuf){
  __shared__ __align__(16) u16 As[4*128*8];   // 8 KB
  __shared__ __align__(16) u16 Bs[4*128*8];   // 8 KB
  const int kblk = blockIdx.y*8 + blockIdx.x;
  const int xc = kblk & 7, bq = (kblk >> 3) & 7, gq = kblk >> 6;
  const int bmi = gq*8 + xc;                  // row-tile index
  const int mt = (M + 127) >> 7;
  if (bmi >= mt) return;
  gemm_tile(A, BT, bias, Cb, M, K, bmi*128, bq*128, As, Bs,
            asrc, adst, sbuf, tbuf);
}

// weight-fusion GEMMs (z=0,1) + fused-bias reductions (z=2) in one launch
__global__ __launch_bounds__(256) void wf_bias_kernel(
    const u16* __restrict__ A0, const u16* __restrict__ B0, u16* __restrict__ C0,
    const u16* __restrict__ A1, const u16* __restrict__ B1, u16* __restrict__ C1,
    const float* __restrict__ bb0, const u16* __restrict__ gwt0,
    const float* __restrict__ bb1, const u16* __restrict__ gwt1,
    float* __restrict__ fb0, float* __restrict__ fb1){
  __shared__ __align__(16) u16 As[4*128*8];
  __shared__ __align__(16) u16 Bs[4*128*8];
  if (blockIdx.z < 2){
    const u16* A = blockIdx.z ? A1 : A0;
    const u16* B = blockIdx.z ? B1 : B0;
    u16* C = blockIdx.z ? C1 : C0;
    gemm_tile(A, B, nullptr, C, HDIM, HDIM, blockIdx.y*128, blockIdx.x*128,
              As, Bs, nullptr, nullptr, nullptr, nullptr);
  } else {
    const int kb = blockIdx.y*8 + blockIdx.x;          // 0..63
    const int wv = threadIdx.x >> 6, lane = threadIdx.x & 63;
    for (int idx = kb*4 + wv; idx < 2*HDIM; idx += 256){
      const int set = idx >> 10, n = idx & (HDIM-1);
      const float* bb = set ? bb1 : bb0;
      const u16* row = (set ? gwt1 : gwt0) + (size_t)n*HDIM + lane*16;
      const float* bp = bb + lane*16;
      float acc = 0.f;
#pragma unroll
      for (int k = 0; k < 16; ++k) acc = fmaf(bp[k], bf2f(row[k]), acc);
      for (int off = 32; off > 0; off >>= 1) acc += __shfl_down(acc, off);
      if (lane == 0) (set ? fb1 : fb0)[n] = acc;
    }
  }
}

// ---------------- GAT aggregation (R5 structure; scalar-addressed gather) -
__global__ __launch_bounds__(256) void gat_agg_kernel(const u16* __restrict__ hlin,
    const float* __restrict__ sbuf, const float* __restrict__ tbuf,
    const int* __restrict__ rowptr, const int* __restrict__ colidx,
    const float* __restrict__ bias, float* __restrict__ outf,
    u16* __restrict__ outbf, u32 seed){
  __shared__ float esh[64*NHEAD];
  __shared__ int   srcs[64];              // byte offsets (node*2048)
  __shared__ float tn[NHEAD], mh[NHEAD], dsum[NHEAD], resc[NHEAD];
  const int n = blockIdx.x;
  const int tid = threadIdx.x;
  const int ht = tid >> 5;                 // head of this thread's 4 dims
  if (tid < NHEAD){
    tn[tid] = tbuf[n*NHEAD + tid];
    mh[tid] = -INFINITY;
    dsum[tid] = 0.0f;
  }
  const int row0 = rowptr[n];
  const int deg = rowptr[n+1] - row0;      // >=1 (self-loop)
  const char* hl = (const char*)hlin;
  const u32 tid8 = (u32)tid*8u;            // per-thread byte offset
  const char* sbase = (const char*)sbuf;
  f32x2 a01 = {0.f,0.f}, a23 = {0.f,0.f};
  f32x2 b01 = {0.f,0.f}, b23 = {0.f,0.f};
  for (int c = 0; c < deg; c += 64){
    const int nc = min(64, deg - c);
    __syncthreads();
    if (tid < nc) srcs[tid] = colidx[row0 + c + tid] << 11;   // *HDIM*2 bytes
    __syncthreads();
    for (int it = tid; it < nc*NHEAD; it += 256){
      int j = it >> 3, hh = it & 7;
      const float* sp = (const float*)(sbase + (srcs[j] >> 6));  // *NHEAD*4 bytes
      float e = sp[hh] + tn[hh];
      esh[it] = (e > 0.f) ? e : 0.2f*e;     // leaky_relu 0.2
    }
    __syncthreads();
    if (tid < 64){                          // wave0: parallel softmax (8 lanes/head)
      const int hh = tid & 7, slot = tid >> 3;
      float mc = -INFINITY;
      for (int j = slot; j < nc; j += 8) mc = fmaxf(mc, esh[j*NHEAD+hh]);
      mc = fmaxf(mc, __shfl_xor(mc, 8));
      mc = fmaxf(mc, __shfl_xor(mc, 16));
      mc = fmaxf(mc, __shfl_xor(mc, 32));
      const float mold = mh[hh];
      const float mnew = fmaxf(mold, mc);
      float wsum = 0.f;
      for (int j = slot; j < nc; j += 8){
        float w = __expf(esh[j*NHEAD+hh] - mnew);
        esh[j*NHEAD+hh] = w;
        wsum += w;
      }
      wsum += __shfl_xor(wsum, 8);
      wsum += __shfl_xor(wsum, 16);
      wsum += __shfl_xor(wsum, 32);
      if (slot == 0){
        float r = (mold == -INFINITY) ? 0.0f : __expf(mold - mnew);
        dsum[hh] = fmaf(dsum[hh], r, wsum);
        mh[hh] = mnew;
        resc[hh] = r;
      }
    }
    __syncthreads();
    const float r = resc[ht];
    const f32x2 r2 = {r, r};
    a01 *= r2; a23 *= r2; b01 *= r2; b23 *= r2;
    int j = 0;
    for (; j + 2 <= nc; j += 2){
      const float w0 = esh[j*NHEAD + ht];
      const float w1 = esh[(j+1)*NHEAD + ht];
      const char* rp0 = hl + (u32)__builtin_amdgcn_readfirstlane(srcs[j]);
      const char* rp1 = hl + (u32)__builtin_amdgcn_readfirstlane(srcs[j+1]);
      const uint2 h0 = *(const uint2*)(rp0 + tid8);
      const uint2 h1 = *(const uint2*)(rp1 + tid8);
      const f32x2 w02 = {w0, w0}, w12 = {w1, w1};
      f32x2 v;
      v.x = __uint_as_float(h0.x << 16); v.y = __uint_as_float(h0.x & 0xffff0000u);
      a01 = __builtin_elementwise_fma(w02, v, a01);
      v.x = __uint_as_float(h0.y << 16); v.y = __uint_as_float(h0.y & 0xffff0000u);
      a23 = __builtin_elementwise_fma(w02, v, a23);
      v.x = __uint_as_float(h1.x << 16); v.y = __uint_as_float(h1.x & 0xffff0000u);
      b01 = __builtin_elementwise_fma(w12, v, b01);
      v.x = __uint_as_float(h1.y << 16); v.y = __uint_as_float(h1.y & 0xffff0000u);
      b23 = __builtin_elementwise_fma(w12, v, b23);
    }
    if (j < nc){
      const float w0 = esh[j*NHEAD + ht];
      const char* rp0 = hl + (u32)__builtin_amdgcn_readfirstlane(srcs[j]);
      const uint2 h0 = *(const uint2*)(rp0 + tid8);
      const f32x2 w02 = {w0, w0};
      f32x2 v;
      v.x = __uint_as_float(h0.x << 16); v.y = __uint_as_float(h0.x & 0xffff0000u);
      a01 = __builtin_elementwise_fma(w02, v, a01);
      v.x = __uint_as_float(h0.y << 16); v.y = __uint_as_float(h0.y & 0xffff0000u);
      a23 = __builtin_elementwise_fma(w02, v, a23);
    }
  }
  float4 acc = make_float4(a01.x + b01.x, a01.y + b01.y,
                           a23.x + b23.x, a23.y + b23.y);
  const float inv = 1.0f / fmaxf(dsum[ht], 1e-16f);
  const float4 bv = *(const float4*)(bias + tid*4);
  float4 o;
  o.x = fmaf(acc.x, inv, bv.x);
  o.y = fmaf(acc.y, inv, bv.y);
  o.z = fmaf(acc.z, inv, bv.z);
  o.w = fmaf(acc.w, inv, bv.w);
  o.x = (o.x > 0.f) ? o.x : __expf(o.x) - 1.0f;   // elu (fast)
  o.y = (o.y > 0.f) ? o.y : __expf(o.y) - 1.0f;
  o.z = (o.z > 0.f) ? o.z : __expf(o.z) - 1.0f;
  o.w = (o.w > 0.f) ? o.w : __expf(o.w) - 1.0f;
  if (outbf){
    const u32 ib = (u32)(n*HDIM + tid*4);
    ushort4 ov;
    ov.x = f2bf(fmaf(0.1f, jax_normal(seed, ib+0u), o.x));
    ov.y = f2bf(fmaf(0.1f, jax_normal(seed, ib+1u), o.y));
    ov.z = f2bf(fmaf(0.1f, jax_normal(seed, ib+2u), o.z));
    ov.w = f2bf(fmaf(0.1f, jax_normal(seed, ib+3u), o.w));
    *(ushort4*)(outbf + (size_t)n*HDIM + tid*4) = ov;
  } else {
    *(float4*)(outf + (size_t)n*HDIM + tid*4) = o;
  }
}

// ---------------- mean pool + classifier (one kernel, LDS gpool) ----------
__global__ __launch_bounds__(256) void pool_clf_kernel(const float* __restrict__ h,
    const int* __restrict__ goff, const int* __restrict__ gcnt,
    const float* __restrict__ W1, const float* __restrict__ b1,
    const float* __restrict__ W2, const float* __restrict__ b2,
    float* __restrict__ out){
  __shared__ float gs[HDIM];
  __shared__ float z[DHID];
  const int g = blockIdx.x, tid = threadIdx.x;
  const int cb = tid*4;
  float4 acc = make_float4(0.f,0.f,0.f,0.f);
  const int n0 = goff[g], n1 = goff[g+1];
  for (int n = n0; n < n1; ++n){
    const float4 v = *(const float4*)(h + (size_t)n*HDIM + cb);
    acc.x += v.x; acc.y += v.y; acc.z += v.z; acc.w += v.w;
  }
  const float invc = 1.0f / fmaxf((float)gcnt[g], 1.0f);
  gs[cb+0] = acc.x*invc; gs[cb+1] = acc.y*invc;
  gs[cb+2] = acc.z*invc; gs[cb+3] = acc.w*invc;
  __syncthreads();
  if (tid < DHID){
    float a = b1[tid];
    for (int k = 0; k < HDIM; ++k) a = fmaf(gs[k], W1[k*DHID + tid], a);
    z[tid] = fmaxf(a, 0.0f);
  }
  __syncthreads();
  if (tid < 2){
    float o = b2[tid];
    for (int k = 0; k < DHID; ++k) o = fmaf(z[k], W2[k*2 + tid], o);
    out[g*2 + tid] = o;
  }
}

// ---------------- launch ----------------
extern "C" void kernel_launch(void* const* d_in, const int* in_sizes, int n_in,
                              void* d_out, int out_size, void* d_ws, size_t ws_size,
                              hipStream_t stream){
  const float* x      = (const float*)d_in[0];
  const int*   ei     = (const int*)d_in[1];
  const int*   batch  = (const int*)d_in[2];
  const float* gatW[3]  = {(const float*)d_in[3],  (const float*)d_in[7],  (const float*)d_in[11]};
  const float* gatB[3]  = {(const float*)d_in[4],  (const float*)d_in[8],  (const float*)d_in[12]};
  const float* asrc[3]  = {(const float*)d_in[5],  (const float*)d_in[9],  (const float*)d_in[13]};
  const float* adst[3]  = {(const float*)d_in[6],  (const float*)d_in[10], (const float*)d_in[14]};
  const float* bootW[2] = {(const float*)d_in[15], (const float*)d_in[17]};
  const float* bootB[2] = {(const float*)d_in[16], (const float*)d_in[18]};
  const float* clfW1 = (const float*)d_in[19];
  const float* clfb1 = (const float*)d_in[20];
  const float* clfW2 = (const float*)d_in[21];
  const float* clfb2 = (const float*)d_in[22];
  float* outp = (float*)d_out;

  // ---- workspace layout ----
  float* fws  = (float*)d_ws;
  float* hB   = fws;                               // N*HD fp32 (GAT L2 out)
  float* sbuf = hB + (size_t)N_NODES*HDIM;         // N*H
  float* tbuf = sbuf + (size_t)N_NODES*NHEAD;      // N*H
  float* fbias0 = tbuf + (size_t)N_NODES*NHEAD;    // HD fp32 (bootB0 @ gatW1)
  float* fbias1 = fbias0 + HDIM;                   // HD fp32 (bootB1 @ gatW2)
  u16* xbf    = (u16*)(fbias1 + HDIM);             // N*DIN bf16
  u16* hAbf   = xbf + (size_t)N_NODES*DIN;         // N*HD bf16 (GAT linear out)
  u16* hBbf   = hAbf + (size_t)N_NODES*HDIM;       // N*HD bf16 (GAT+noise out)
  u16* wt[3];
  wt[0] = hBbf + (size_t)N_NODES*HDIM;             // gatW0^T [1024,64]
  wt[1] = wt[0] + (size_t)HDIM*DIN;                // gatW1^T [1024,1024]
  wt[2] = wt[1] + (size_t)HDIM*HDIM;               // gatW2^T
  u16* wnt0   = wt[2] + (size_t)HDIM*HDIM;         // bootW0 bf16 (row-major)
  u16* wnt1   = wnt0 + (size_t)HDIM*HDIM;          // bootW1 bf16 (row-major)
  u16* wf0    = wnt1 + (size_t)HDIM*HDIM;          // (bootW0@gatW1)^T bf16
  u16* wf1    = wf0 + (size_t)HDIM*HDIM;           // (bootW1@gatW2)^T bf16
  int* rowptr = (int*)(wf1 + (size_t)HDIM*HDIM);   // N+1
  int* cursor = rowptr + (N_NODES+1);              // N
  int* colidx = cursor + N_NODES;                  // E_TOT
  int* gcnt   = colidx + E_TOT;                    // G   (adjacent to cnt: one memset)
  int* cnt    = gcnt + NGRAPH;                     // N
  int* goff   = cnt + N_NODES;                     // G+1

  hipMemsetAsync(gcnt, 0, (NGRAPH + N_NODES)*sizeof(int), stream);

  const int nb_e = (N_EDGES + 255)/256;

  // converts (x, bootW0, bootW1) + CSR/graph counts in one launch
  prep_misc_kernel<<<dim3((E_TOT + 255)/256, 4), 256, 0, stream>>>(
      x, bootW[0], bootW[1], xbf, wnt0, wnt1, ei, batch, cnt, gcnt);
  transpose_all_kernel<<<dim3(HDIM/32, HDIM/32, 3), 256, 0, stream>>>(
      gatW[0], gatW[1], gatW[2], wt[0], wt[1], wt[2]);
  scan_pair_kernel<<<2, 1024, 0, stream>>>(cnt, rowptr, cursor, colidx, gcnt, goff);
  fill_edges_kernel<<<nb_e, 256, 0, stream>>>(ei, cursor, colidx);

  // fused weights wf[n,k] = sum_m gatW^T[n,m]*bootW[k,m] + fused biases
  wf_bias_kernel<<<dim3(8, 8, 3), 256, 0, stream>>>(
      wt[1], wnt0, wf0, wt[2], wnt1, wf1,
      bootB[0], wt[1], bootB[1], wt[2], fbias0, fbias1);

  // swizzled grid: 8 col-tiles x (row-tiles padded to multiple of 8)
  const int mt = (N_NODES + 127)/128;              // 157
  dim3 gemmGrid(8, (mt + 7)/8*8);                  // (8, 160)

  // L0 (gemm with fused s/t epilogue)
  gemm_bf16<<<gemmGrid, 256, 0, stream>>>(xbf, wt[0], nullptr, hAbf, N_NODES, DIN,
                                          asrc[0], adst[0], sbuf, tbuf);
  gat_agg_kernel<<<N_NODES, 256, 0, stream>>>(hAbf, sbuf, tbuf, rowptr, colidx,
                                              gatB[0], nullptr, hBbf, 100u);
  // L1 (fused boot0+gat1 linear)
  gemm_bf16<<<gemmGrid, 256, 0, stream>>>(hBbf, wf0, fbias0, hAbf, N_NODES, HDIM,
                                          asrc[1], adst[1], sbuf, tbuf);
  gat_agg_kernel<<<N_NODES, 256, 0, stream>>>(hAbf, sbuf, tbuf, rowptr, colidx,
                                              gatB[1], nullptr, hBbf, 101u);
  // L2 (fused boot1+gat2 linear)
  gemm_bf16<<<gemmGrid, 256, 0, stream>>>(hBbf, wf1, fbias1, hAbf, N_NODES, HDIM,
                                          asrc[2], adst[2], sbuf, tbuf);
  gat_agg_kernel<<<N_NODES, 256, 0, stream>>>(hAbf, sbuf, tbuf, rowptr, colidx,
                                              gatB[2], hB, nullptr, 0u);

  pool_clf_kernel<<<NGRAPH, 256, 0, stream>>>(hB, goff, gcnt,
                                              clfW1, clfb1, clfW2, clfb2, outp);
}